// Round 1
// baseline (370.110 us; speedup 1.0000x reference)
//
#include <hip/hip_runtime.h>

// Polar encoder: N=1024, K=512, BATCH=65536.
// Per row: scatter info bits -> 1024-bit codeword -> 10-stage XOR butterfly.
// Bit-packed: 32 uint32 words per row; one wave handles 2 rows
// (lanes 0-31 = row A words 0-31, lanes 32-63 = row B words 0-31).

#define PN     1024
#define PK     512
#define PBATCH 65536
#define WORDS  32   // PN/32

__global__ __launch_bounds__(256) void polar_encode_kernel(
    const float* __restrict__ u,
    const int*   __restrict__ info_pos,
    float*       __restrict__ out)
{
    // --- build inverse scatter map (codeword pos -> info bit index, -1 if frozen)
    __shared__ int inv[PN];
    const int tid = threadIdx.x;
    #pragma unroll
    for (int i = tid; i < PN; i += 256) inv[i] = -1;
    __syncthreads();
    #pragma unroll
    for (int k = tid; k < PK; k += 256) inv[info_pos[k]] = k;
    __syncthreads();

    const int lane = tid & 63;
    const int wave = tid >> 6;
    const int l31  = lane & 31;
    const int half = lane >> 5;                       // 0 = row A, 1 = row B
    const long rA  = (long)blockIdx.x * 8 + wave * 2; // first row of this wave's pair
    const long row = rA + half;                       // row this half-wave loads
    const float* urow = u + row * (long)PK;

    // --- gather + pack: round c builds codeword word c of both rows via ballot
    unsigned int word = 0;
    #pragma unroll 8
    for (int c = 0; c < WORDS; ++c) {
        const int p  = c * 32 + l31;   // codeword bit position
        const int iv = inv[p];
        float v = 0.0f;
        if (iv >= 0) v = urow[iv];
        const unsigned long long m = __ballot(v != 0.0f);
        const unsigned int sel = half ? (unsigned int)(m >> 32) : (unsigned int)m;
        if (l31 == c) word = sel;      // lane c keeps row A word c; lane 32+c keeps row B word c
    }

    // --- butterfly stages 0..4: bit distance 1,2,4,8,16 (in-word)
    word ^= (word >> 1)  & 0x55555555u;
    word ^= (word >> 2)  & 0x33333333u;
    word ^= (word >> 4)  & 0x0F0F0F0Fu;
    word ^= (word >> 8)  & 0x00FF00FFu;
    word ^= (word >> 16) & 0x0000FFFFu;

    // --- butterfly stages 5..9: word distance 1,2,4,8,16 (cross-lane)
    // lower half of each 2*off block XORs in the upper half; off<=16 so
    // lane^off never crosses the 32-lane row boundary.
    #pragma unroll
    for (int off = 1; off <= 16; off <<= 1) {
        const unsigned int partner =
            (unsigned int)__shfl_xor((int)word, off, 64);
        if ((l31 & off) == 0) word ^= partner;
    }

    // --- coalesced float4 store: f = float4 index within the 2-row pair
    float4* out4 = (float4*)out;
    const long base = rA * (PN / 4);   // rA * 256
    #pragma unroll
    for (int j = 0; j < 8; ++j) {
        const int f   = j * 64 + lane;      // 0..511
        const int r   = f >> 8;             // which row of the pair
        const int wir = (f & 255) >> 3;     // word index within row
        const int src = wir + (r << 5);     // lane holding that word
        const unsigned int b   = (unsigned int)__shfl((int)word, src, 64);
        const unsigned int nib = (b >> ((lane & 7) * 4)) & 0xFu;
        float4 v;
        v.x = (nib & 1u) ? 1.0f : 0.0f;
        v.y = (nib & 2u) ? 1.0f : 0.0f;
        v.z = (nib & 4u) ? 1.0f : 0.0f;
        v.w = (nib & 8u) ? 1.0f : 0.0f;
        out4[base + f] = v;
    }
}

extern "C" void kernel_launch(void* const* d_in, const int* in_sizes, int n_in,
                              void* d_out, int out_size, void* d_ws, size_t ws_size,
                              hipStream_t stream) {
    const float* u        = (const float*)d_in[0];
    const int*   info_pos = (const int*)d_in[1];
    // d_in[2] = ind_gather — unused; butterfly structure is compiled in.
    float* out = (float*)d_out;

    const int blocks = PBATCH / 8;  // each block (4 waves) handles 8 rows
    polar_encode_kernel<<<blocks, 256, 0, stream>>>(u, info_pos, out);
}